// Round 11
// baseline (206.825 us; speedup 1.0000x reference)
//
#include <hip/hip_runtime.h>

// ============================================================================
// LeViT attention, MI355X. I/O tensors are FLOAT32 (per reference).
// b=2, C=256, H=W=56, n=3136, heads=8, kd=16, dh=64.
// Pipeline: xtw (x->x_t bf16 + W'=s*W bf16) -> qkv (MFMA, no LDS, q scaled by
// log2e) -> attn (flash; r10 proven DMA/vmcnt/s_barrier protocol, now with
// INTRA-BLOCK SPLIT-K: 8 waves = 2 pipelines x 4 waves, additive merge) ->
// proj (MFMA, no LDS, fp32 out).
// ws (u16 elems): qws 802816 | kws 802816 | vws 3211264 | R 3211264
//   (R = x_t during xtw/qkv, o_t from attn on) | wqb 32768 | wkb 32768 |
//   wvb 131072 | wpb 131072   => 16,711,680 B
// MFMA 16x16x32_bf16: A[m=l15][k=quad*8+j]; B[k=quad*8+j][n=l15];
// C/D: col=l15, row=quad*4+reg.
// attn key relabeling (r9/r10 proven): P = concat of two S^T C-tiles; V in
// LDS interleaved, octet o_rel of row d at o_rel^(d&7) (conflict-free b128).
// ============================================================================

typedef short  s16x8 __attribute__((ext_vector_type(8)));
typedef float  f32x4 __attribute__((ext_vector_type(4)));
typedef unsigned short u16;
typedef unsigned short u16x4 __attribute__((ext_vector_type(4)));

__device__ __forceinline__ u16 f2bf(float f) {   // RNE
    unsigned u = __builtin_bit_cast(unsigned, f);
    u += 0x7FFF + ((u >> 16) & 1);
    return (u16)(u >> 16);
}
__device__ __forceinline__ u16 f2bf_h(float f) { // round-half-up (cheap, p>0)
    unsigned u = __builtin_bit_cast(unsigned, f);
    return (u16)((u + 0x8000) >> 16);
}
__device__ __forceinline__ f32x4 mfma32(s16x8 a, s16x8 b, f32x4 c) {
    return __builtin_amdgcn_mfma_f32_16x16x32_bf16(a, b, c, 0, 0, 0);
}
__device__ __forceinline__ void stage16(const u16* g, u16* l) {
    __builtin_amdgcn_global_load_lds(
        (const __attribute__((address_space(1))) unsigned int*)g,
        (__attribute__((address_space(3))) unsigned int*)l, 16, 0, 0);
}
__device__ __forceinline__ void stage4(const u16* g, u16* l) {
    __builtin_amdgcn_global_load_lds(
        (const __attribute__((address_space(1))) unsigned int*)g,
        (__attribute__((address_space(3))) unsigned int*)l, 4, 0, 0);
}

// ---------------------------------------------------------------------------
// Fused: z<2 -> x fp32 -> x_t[b][3136][256] bf16 transpose; z==2 -> W'=s*W.
// grid (49,4,3), 256 thr.
// ---------------------------------------------------------------------------
__global__ __launch_bounds__(256) void xtw_kernel(
    const float* __restrict__ x, u16* __restrict__ xt,
    const float* __restrict__ wq, const float* __restrict__ sq,
    const float* __restrict__ wk, const float* __restrict__ sk,
    const float* __restrict__ wv, const float* __restrict__ sv,
    const float* __restrict__ wp, const float* __restrict__ sp,
    u16* __restrict__ wqb, u16* __restrict__ wkb,
    u16* __restrict__ wvb, u16* __restrict__ wpb)
{
    const int t = threadIdx.x;
    if (blockIdx.z == 2) {
        const int base = (blockIdx.y * 49 + blockIdx.x) * 256 + t;
        for (int idx = base; idx < 327680; idx += 50176) {
            if (idx < 32768)        wqb[idx] = f2bf(wq[idx] * sq[idx >> 8]);
            else if (idx < 65536)  { int j = idx - 32768;  wkb[j] = f2bf(wk[j] * sk[j >> 8]); }
            else if (idx < 196608) { int j = idx - 65536;  wvb[j] = f2bf(wv[j] * sv[j >> 8]); }
            else                   { int j = idx - 196608; wpb[j] = f2bf(wp[j] * sp[j >> 9]); }
        }
        return;
    }
    const int b = blockIdx.z, c0 = blockIdx.y * 64, n0 = blockIdx.x * 64;
    __shared__ float lds[64][65];
    const int nl = t & 63, cl = t >> 6;
    #pragma unroll
    for (int i = 0; i < 16; i++) {
        const int c = cl + i * 4;
        lds[c][nl] = x[(b * 256 + c0 + c) * 3136 + n0 + nl];
    }
    __syncthreads();
    #pragma unroll
    for (int i = 0; i < 16; i++) {
        const int n = cl + i * 4;
        xt[(b * 3136 + n0 + n) * 256 + c0 + nl] = f2bf(lds[nl][n]);
    }
}

// ---------------------------------------------------------------------------
// QKV MFMA GEMM, no LDS. grid (49 n-tiles, 12 rt, 2 b), 256 thr.
// rt 0..3: q/k (token-major store; q pre-scaled by log2e); rt 4..11: v.
// ---------------------------------------------------------------------------
__global__ __launch_bounds__(256, 4) void qkv_kernel(
    const u16* __restrict__ xt,
    const u16* __restrict__ wqb, const u16* __restrict__ wkb, const u16* __restrict__ wvb,
    const float* __restrict__ bq, const float* __restrict__ bk, const float* __restrict__ bv,
    u16* __restrict__ qws, u16* __restrict__ kws, u16* __restrict__ vws)
{
    const int b = blockIdx.z, rt = blockIdx.y, n0 = blockIdx.x * 64;
    const int t = threadIdx.x, wave = t >> 6, lane = t & 63;
    const int l15 = lane & 15, quad = lane >> 4;
    const f32x4 z = {0.f, 0.f, 0.f, 0.f};

    if (rt < 4) {
        const u16* wb      = (rt < 2) ? wqb : wkb;
        const float* bias  = (rt < 2) ? bq : bk;
        u16* dst           = (rt < 2) ? qws : kws;
        const float qs     = (rt < 2) ? 1.44269504088896f : 1.0f;  // fold log2e
        const int och0 = (rt & 1) * 64;
        const int m0   = n0 + wave * 16;
        const u16* xrow = &xt[(b * 3136 + m0 + l15) * 256 + quad * 8];
        f32x4 acc[4] = {z, z, z, z};
        #pragma unroll
        for (int kc = 0; kc < 256; kc += 32) {
            s16x8 a = *(const s16x8*)&xrow[kc];
            #pragma unroll
            for (int f = 0; f < 4; f++) {
                s16x8 bf = *(const s16x8*)&wb[(och0 + f * 16 + l15) * 256 + kc + quad * 8];
                acc[f] = mfma32(a, bf, acc[f]);
            }
        }
        #pragma unroll
        for (int f = 0; f < 4; f++) {
            const int och = och0 + f * 16 + l15;
            const float bi = bias[och];
            const int h = och >> 4;
            #pragma unroll
            for (int r = 0; r < 4; r++) {
                const int tok = m0 + quad * 4 + r;
                dst[((b * 8 + h) * 3136 + tok) * 16 + l15] = f2bf((acc[f][r] + bi) * qs);
            }
        }
    } else {
        const int och0 = (rt - 4) * 64 + wave * 16;
        const u16* arow = &wvb[(och0 + l15) * 256 + quad * 8];
        f32x4 acc[4] = {z, z, z, z};
        #pragma unroll
        for (int kc = 0; kc < 256; kc += 32) {
            s16x8 a = *(const s16x8*)&arow[kc];
            #pragma unroll
            for (int f = 0; f < 4; f++) {
                s16x8 bf = *(const s16x8*)&xt[(b * 3136 + n0 + f * 16 + l15) * 256 + kc + quad * 8];
                acc[f] = mfma32(a, bf, acc[f]);
            }
        }
        #pragma unroll
        for (int r = 0; r < 4; r++) {
            const int och = och0 + quad * 4 + r;
            const float bi = bv[och];
            #pragma unroll
            for (int f = 0; f < 4; f++) {
                const int tok = n0 + f * 16 + l15;
                vws[(b * 512 + och) * 3136 + tok] = f2bf(acc[f][r] + bi);
            }
        }
    }
}

// ---------------------------------------------------------------------------
// Flash attention v10 = r10 protocol + intra-block split-K.
// grid (16 bh, 49 q-tiles of 64); 512 thr = 2 pipelines x 4 waves.
// Pipeline g=0: key-chunks 0..23 (+1 zeroed pad iter); g=1: chunks 24..48.
// Each pipeline: triple-buffered LDS via global_load_lds (9 DMA/wave/chunk),
// one raw s_barrier + vmcnt(9) per iteration (25 total). Additive merge of
// the two halves' O/rsum via LDS (staging memory reused after drain).
// ---------------------------------------------------------------------------
__global__ __launch_bounds__(512, 4) void attn_kernel(
    const u16* __restrict__ qws, const u16* __restrict__ kws,
    const u16* __restrict__ vws, u16* __restrict__ o_t)
{
    const int bh   = blockIdx.x;                 // x fastest -> XCD = bh%8
    const int tile = blockIdx.y;
    const int t    = threadIdx.x;
    const int wave = t >> 6;                     // 0..7
    const int g    = wave >> 2;                  // pipeline (key half)
    const int w4   = wave & 3;                   // wave within pipeline
    const int lane = t & 63;
    const int l15  = lane & 15, quad = lane >> 4;
    const int nb   = tile * 64 + w4 * 16;        // this wave's query base

    // per pipeline, per buffer: K 1024 u16 | V 4096 u16 (interleaved slots)
    __shared__ __align__(16) u16 stg[2][3][5120];

    const u16* kb = &kws[bh * 3136 * 16];
    const u16* vb = &vws[bh * 64 * 3136];

    // K staging (r10 proven): 1 x 16B DMA per wave, wave pairs duplicate
    const int weff  = w4 & 1;
    const int kkey  = lane >> 1;
    const int khalf = (lane & 1) ^ ((lane >> 3) & 1);
    const int kdst  = weff * 512;
    const int ksrc_row = weff * 32 + kkey;

    // V staging (r10 proven): 8 x 4B DMA per wave, relabel+row-xor placement
    const int vrow_off = lane >> 5;
    const int dwpos = lane & 31;
    const int p_oct = dwpos >> 2, w_i = dwpos & 3;

    // Q fragment (B-op): B[k=d=quad*8+j][n=query=l15]; zero for d>=16
    s16x8 aq = {0, 0, 0, 0, 0, 0, 0, 0};
    if (quad < 2)
        aq = *(const s16x8*)&qws[(bh * 3136 + nb + l15) * 16 + quad * 8];
    s16x8 ones;
    #pragma unroll
    for (int i = 0; i < 8; i++) ones[i] = (short)0x3F80;   // bf16 1.0

    f32x4 acc[4], acc5;                          // O^T tiles + rowsum tile
    #pragma unroll
    for (int dt = 0; dt < 4; dt++) acc[dt] = (f32x4){0.f, 0.f, 0.f, 0.f};
    acc5 = (f32x4){0.f, 0.f, 0.f, 0.f};

    const int lim   = g ? 24 : 23;               // last valid chunk index
    const int cbase = g * 24;                    // pipeline's first chunk

    auto stage_chunk = [&](int ci, int buf) {
        const int cc = (ci < lim) ? ci : lim;    // clamp (pad iters re-stage)
        const int kbase = (cbase + cc) * 64;
        u16* sb = &stg[g][buf][0];
        #pragma unroll
        for (int s = 0; s < 2; s++) {
            #pragma unroll
            for (int h = 0; h < 4; h++) {
                const int m = (w4 + s * 4) * 4 + h;          // pair idx 0..31
                const int d = 2 * m + vrow_off;
                const int gg = p_oct ^ (d & 7);
                const int src_dw = (gg >> 2) * 16 + ((w_i >> 1) & 1) * 8 +
                                   (gg & 3) * 2 + (w_i & 1);
                stage4(vb + d * 3136 + kbase + src_dw * 2, &sb[1024 + m * 128]);
            }
        }
        stage16(kb + (kbase + ksrc_row) * 16 + khalf * 8, &sb[kdst]);
    };

    stage_chunk(0, 0);
    stage_chunk(1, 1);
    __builtin_amdgcn_s_waitcnt(0x0F79);          // vmcnt(9): my chunk-0 DMAs done

    for (int i = 0; i < 25; i++) {
        __builtin_amdgcn_s_barrier();            // chunk i certified block-wide
        stage_chunk(i + 2, (i + 2) % 3);
        __builtin_amdgcn_s_waitcnt(0x0F79);      // vmcnt(9): chunk i+1 landed

        const u16* kc_ = &stg[g][i % 3][0];
        const u16* vc_ = &stg[g][i % 3][1024];
        const f32x4 z = {0.f, 0.f, 0.f, 0.f};

        // ---- S^T = K·Q^T : 4 key tiles of 16 (swapped operands)
        f32x4 s[4];
        #pragma unroll
        for (int ii = 0; ii < 4; ii++) {
            s16x8 kf = *(const s16x8*)&kc_[(ii * 16 + l15) * 16 +
                                           (((quad & 1) ^ ((l15 >> 2) & 1)) * 8)];
            s[ii] = mfma32(kf, aq, z);
        }

        // ---- P pack: pf[c32] = {exp2 s[2c32], exp2 s[2c32+1]}
        s16x8 pf[2];
        #pragma unroll
        for (int c32 = 0; c32 < 2; c32++) {
            #pragma unroll
            for (int r = 0; r < 4; r++) {
                pf[c32][r]     = (short)f2bf_h(__builtin_amdgcn_exp2f(s[2 * c32][r]));
                pf[c32][4 + r] = (short)f2bf_h(__builtin_amdgcn_exp2f(s[2 * c32 + 1][r]));
            }
        }
        if (g == 0 && i == 24) {                 // pad iteration: contribute 0
            pf[0] = (s16x8){0, 0, 0, 0, 0, 0, 0, 0};
            pf[1] = (s16x8){0, 0, 0, 0, 0, 0, 0, 0};
        }

        // ---- O^T += V^T·P ; rowsum via ones-MFMA
        #pragma unroll
        for (int c32 = 0; c32 < 2; c32++) {
            #pragma unroll
            for (int dt = 0; dt < 4; dt++) {
                const int d = dt * 16 + l15;
                const int pos = ((c32 * 4 + quad) ^ (d & 7)) * 8;
                s16x8 vf = *(const s16x8*)&vc_[d * 64 + pos];
                acc[dt] = mfma32(vf, pf[c32], acc[dt]);
            }
            acc5 = mfma32(ones, pf[c32], acc5);
        }
    }

    // ---- drain all DMA (stray pad stages) before repurposing LDS
    __builtin_amdgcn_s_waitcnt(0x0F70);          // vmcnt(0)
    __syncthreads();

    // ---- additive merge: pipeline 1 publishes, pipeline 0 combines+writes
    float* mbuf = (float*)&stg[0][0][0];         // [4 waves][64 lanes][17] f32
    if (g == 1) {
        float* mw = &mbuf[(w4 * 64 + lane) * 17];
        #pragma unroll
        for (int dt = 0; dt < 4; dt++)
            #pragma unroll
            for (int r = 0; r < 4; r++) mw[dt * 4 + r] = acc[dt][r];
        mw[16] = acc5[0];
    }
    __syncthreads();
    if (g == 0) {
        const float* mw = &mbuf[(w4 * 64 + lane) * 17];
        const float inv = 1.0f / (acc5[0] + mw[16]);
        u16* dst = &o_t[(((bh >> 3) * 3136) + nb + l15) * 512 + (bh & 7) * 64];
        #pragma unroll
        for (int dt = 0; dt < 4; dt++) {
            u16x4 o4;
            #pragma unroll
            for (int r = 0; r < 4; r++)
                o4[r] = f2bf((acc[dt][r] + mw[dt * 4 + r]) * inv);
            *(u16x4*)&dst[dt * 16 + quad * 4] = o4;
        }
    }
}

// ---------------------------------------------------------------------------
// Output projection MFMA GEMM, no LDS. grid (98 n-tiles of 32, 4 och, 2 b).
// ---------------------------------------------------------------------------
__global__ __launch_bounds__(256, 4) void proj_kernel(
    const u16* __restrict__ o_t, const u16* __restrict__ wpb,
    const float* __restrict__ bp, float* __restrict__ out)
{
    const int b = blockIdx.z, n0 = blockIdx.x * 32;
    const int och0 = blockIdx.y * 64 + (threadIdx.x >> 6) * 16;
    const int lane = threadIdx.x & 63;
    const int l15 = lane & 15, quad = lane >> 4;
    const f32x4 z = {0.f, 0.f, 0.f, 0.f};

    const u16* arow = &wpb[(och0 + l15) * 512 + quad * 8];
    f32x4 acc[2] = {z, z};
    #pragma unroll 4
    for (int kc = 0; kc < 512; kc += 32) {
        s16x8 a = *(const s16x8*)&arow[kc];
        #pragma unroll
        for (int f = 0; f < 2; f++) {
            s16x8 bf = *(const s16x8*)&o_t[(b * 3136 + n0 + f * 16 + l15) * 512 + kc + quad * 8];
            acc[f] = mfma32(a, bf, acc[f]);
        }
    }
    #pragma unroll
    for (int r = 0; r < 4; r++) {
        const int och = och0 + quad * 4 + r;
        const float bi = bp[och];
        #pragma unroll
        for (int f = 0; f < 2; f++)
            out[(b * 256 + och) * 3136 + n0 + f * 16 + l15] = acc[f][r] + bi;
    }
}

// ---------------------------------------------------------------------------
extern "C" void kernel_launch(void* const* d_in, const int* in_sizes, int n_in,
                              void* d_out, int out_size, void* d_ws, size_t ws_size,
                              hipStream_t stream) {
    const float* x  = (const float*)d_in[0];
    const float* wq = (const float*)d_in[1];
    const float* sq = (const float*)d_in[2];
    const float* bq = (const float*)d_in[3];
    const float* wk = (const float*)d_in[4];
    const float* sk = (const float*)d_in[5];
    const float* bk = (const float*)d_in[6];
    const float* wv = (const float*)d_in[7];
    const float* sv = (const float*)d_in[8];
    const float* bv = (const float*)d_in[9];
    const float* wp = (const float*)d_in[10];
    const float* sp = (const float*)d_in[11];
    const float* bp = (const float*)d_in[12];
    float* out = (float*)d_out;

    u16* qws = (u16*)d_ws;                 // 802816
    u16* kws = qws + 802816;               // 802816
    u16* vws = kws + 802816;               // 3211264
    u16* R   = vws + 3211264;              // 3211264 (x_t then o_t, overlaid)
    u16* xt  = R;
    u16* ot  = R;
    u16* wqb = R + 3211264;                // 32768
    u16* wkb = wqb + 32768;                // 32768
    u16* wvb = wkb + 32768;                // 131072
    u16* wpb = wvb + 131072;               // 131072  (total 16,711,680 B)

    xtw_kernel<<<dim3(49, 4, 3), 256, 0, stream>>>(x, xt, wq, sq, wk, sk,
                                                   wv, sv, wp, sp,
                                                   wqb, wkb, wvb, wpb);
    qkv_kernel<<<dim3(49, 12, 2), 256, 0, stream>>>(xt, wqb, wkb, wvb,
                                                    bq, bk, bv, qws, kws, vws);
    attn_kernel<<<dim3(16, 49), 512, 0, stream>>>(qws, kws, vws, ot);
    proj_kernel<<<dim3(98, 4, 2), 256, 0, stream>>>(ot, wpb, bp, out);
}

// Round 12
// 201.799 us; speedup vs baseline: 1.0249x; 1.0249x over previous
//
#include <hip/hip_runtime.h>

// ============================================================================
// LeViT attention, MI355X. I/O tensors are FLOAT32 (per reference).
// b=2, C=256, H=W=56, n=3136, heads=8, kd=16, dh=64.
// Pipeline: xtw (x->x_t bf16 + W'=s*W bf16) -> qkv (MFMA, no LDS, q scaled by
// log2e, A-frags hoisted) -> attn (flash; r10 proven DMA/layout protocol, now
// 128-key double-buffered iterations: 25 barriers, 2 independent chunk
// pipelines per iteration for ILP) -> proj (MFMA, no LDS, A hoisted).
// ws (u16 elems): qws 802816 | kws 802816 | vws 3211264 | R 3211264
//   (R = x_t during xtw/qkv, o_t from attn on) | wqb 32768 | wkb 32768 |
//   wvb 131072 | wpb 131072   => 16,711,680 B
// MFMA 16x16x32_bf16: A[m=l15][k=quad*8+j]; B[k=quad*8+j][n=l15];
// C/D: col=l15, row=quad*4+reg.
// attn key relabeling (r9/r10 proven): P = concat of two S^T C-tiles; V in
// LDS interleaved, octet o_rel of row d at o_rel^(d&7) (conflict-free b128).
// ============================================================================

typedef short  s16x8 __attribute__((ext_vector_type(8)));
typedef float  f32x4 __attribute__((ext_vector_type(4)));
typedef unsigned short u16;
typedef unsigned short u16x4 __attribute__((ext_vector_type(4)));

__device__ __forceinline__ u16 f2bf(float f) {   // RNE
    unsigned u = __builtin_bit_cast(unsigned, f);
    u += 0x7FFF + ((u >> 16) & 1);
    return (u16)(u >> 16);
}
__device__ __forceinline__ u16 f2bf_h(float f) { // round-half-up (cheap, p>0)
    unsigned u = __builtin_bit_cast(unsigned, f);
    return (u16)((u + 0x8000) >> 16);
}
__device__ __forceinline__ f32x4 mfma32(s16x8 a, s16x8 b, f32x4 c) {
    return __builtin_amdgcn_mfma_f32_16x16x32_bf16(a, b, c, 0, 0, 0);
}
__device__ __forceinline__ void stage16(const u16* g, u16* l) {
    __builtin_amdgcn_global_load_lds(
        (const __attribute__((address_space(1))) unsigned int*)g,
        (__attribute__((address_space(3))) unsigned int*)l, 16, 0, 0);
}
__device__ __forceinline__ void stage4(const u16* g, u16* l) {
    __builtin_amdgcn_global_load_lds(
        (const __attribute__((address_space(1))) unsigned int*)g,
        (__attribute__((address_space(3))) unsigned int*)l, 4, 0, 0);
}

// ---------------------------------------------------------------------------
// Fused: z<2 -> x fp32 -> x_t[b][3136][256] bf16 transpose; z==2 -> W'=s*W.
// grid (49,4,3), 256 thr.
// ---------------------------------------------------------------------------
__global__ __launch_bounds__(256) void xtw_kernel(
    const float* __restrict__ x, u16* __restrict__ xt,
    const float* __restrict__ wq, const float* __restrict__ sq,
    const float* __restrict__ wk, const float* __restrict__ sk,
    const float* __restrict__ wv, const float* __restrict__ sv,
    const float* __restrict__ wp, const float* __restrict__ sp,
    u16* __restrict__ wqb, u16* __restrict__ wkb,
    u16* __restrict__ wvb, u16* __restrict__ wpb)
{
    const int t = threadIdx.x;
    if (blockIdx.z == 2) {
        const int base = (blockIdx.y * 49 + blockIdx.x) * 256 + t;
        for (int idx = base; idx < 327680; idx += 50176) {
            if (idx < 32768)        wqb[idx] = f2bf(wq[idx] * sq[idx >> 8]);
            else if (idx < 65536)  { int j = idx - 32768;  wkb[j] = f2bf(wk[j] * sk[j >> 8]); }
            else if (idx < 196608) { int j = idx - 65536;  wvb[j] = f2bf(wv[j] * sv[j >> 8]); }
            else                   { int j = idx - 196608; wpb[j] = f2bf(wp[j] * sp[j >> 9]); }
        }
        return;
    }
    const int b = blockIdx.z, c0 = blockIdx.y * 64, n0 = blockIdx.x * 64;
    __shared__ float lds[64][65];
    const int nl = t & 63, cl = t >> 6;
    #pragma unroll
    for (int i = 0; i < 16; i++) {
        const int c = cl + i * 4;
        lds[c][nl] = x[(b * 256 + c0 + c) * 3136 + n0 + nl];
    }
    __syncthreads();
    #pragma unroll
    for (int i = 0; i < 16; i++) {
        const int n = cl + i * 4;
        xt[(b * 3136 + n0 + n) * 256 + c0 + nl] = f2bf(lds[nl][n]);
    }
}

// ---------------------------------------------------------------------------
// QKV MFMA GEMM, no LDS, A-frags hoisted. grid (49 n-tiles, 12 rt, 2 b).
// rt 0..3: q/k (token-major store; q pre-scaled by log2e); rt 4..11: v.
// ---------------------------------------------------------------------------
__global__ __launch_bounds__(256, 4) void qkv_kernel(
    const u16* __restrict__ xt,
    const u16* __restrict__ wqb, const u16* __restrict__ wkb, const u16* __restrict__ wvb,
    const float* __restrict__ bq, const float* __restrict__ bk, const float* __restrict__ bv,
    u16* __restrict__ qws, u16* __restrict__ kws, u16* __restrict__ vws)
{
    const int b = blockIdx.z, rt = blockIdx.y, n0 = blockIdx.x * 64;
    const int t = threadIdx.x, wave = t >> 6, lane = t & 63;
    const int l15 = lane & 15, quad = lane >> 4;
    const f32x4 z = {0.f, 0.f, 0.f, 0.f};

    if (rt < 4) {
        const u16* wb      = (rt < 2) ? wqb : wkb;
        const float* bias  = (rt < 2) ? bq : bk;
        u16* dst           = (rt < 2) ? qws : kws;
        const float qs     = (rt < 2) ? 1.44269504088896f : 1.0f;  // fold log2e
        const int och0 = (rt & 1) * 64;
        const int m0   = n0 + wave * 16;
        const u16* xrow = &xt[(b * 3136 + m0 + l15) * 256 + quad * 8];
        s16x8 a8[8];
        #pragma unroll
        for (int kc8 = 0; kc8 < 8; kc8++) a8[kc8] = *(const s16x8*)&xrow[kc8 * 32];
        f32x4 acc[4] = {z, z, z, z};
        #pragma unroll
        for (int kc8 = 0; kc8 < 8; kc8++) {
            #pragma unroll
            for (int f = 0; f < 4; f++) {
                s16x8 bf = *(const s16x8*)&wb[(och0 + f * 16 + l15) * 256 + kc8 * 32 + quad * 8];
                acc[f] = mfma32(a8[kc8], bf, acc[f]);
            }
        }
        #pragma unroll
        for (int f = 0; f < 4; f++) {
            const int och = och0 + f * 16 + l15;
            const float bi = bias[och];
            const int h = och >> 4;
            #pragma unroll
            for (int r = 0; r < 4; r++) {
                const int tok = m0 + quad * 4 + r;
                dst[((b * 8 + h) * 3136 + tok) * 16 + l15] = f2bf((acc[f][r] + bi) * qs);
            }
        }
    } else {
        const int och0 = (rt - 4) * 64 + wave * 16;
        const u16* arow = &wvb[(och0 + l15) * 256 + quad * 8];
        s16x8 a8[8];
        #pragma unroll
        for (int kc8 = 0; kc8 < 8; kc8++) a8[kc8] = *(const s16x8*)&arow[kc8 * 32];
        f32x4 acc[4] = {z, z, z, z};
        #pragma unroll
        for (int kc8 = 0; kc8 < 8; kc8++) {
            #pragma unroll
            for (int f = 0; f < 4; f++) {
                s16x8 bf = *(const s16x8*)&xt[(b * 3136 + n0 + f * 16 + l15) * 256 + kc8 * 32 + quad * 8];
                acc[f] = mfma32(a8[kc8], bf, acc[f]);
            }
        }
        #pragma unroll
        for (int r = 0; r < 4; r++) {
            const int och = och0 + quad * 4 + r;
            const float bi = bv[och];
            #pragma unroll
            for (int f = 0; f < 4; f++) {
                const int tok = n0 + f * 16 + l15;
                vws[(b * 512 + och) * 3136 + tok] = f2bf(acc[f][r] + bi);
            }
        }
    }
}

// ---------------------------------------------------------------------------
// Flash attention v11 = r10 protocol, 128-key double-buffered iterations.
// grid (16 bh, 49 q-tiles of 64); 4 waves; 25 iterations x 2 chunks of 64.
// Per iteration: s_barrier; stage next pair (18 DMA/wave); compute 2 chunks
// (independent pipelines -> ILP); vmcnt(0) on own DMAs (issued early - free).
// ---------------------------------------------------------------------------
__global__ __launch_bounds__(256, 4) void attn_kernel(
    const u16* __restrict__ qws, const u16* __restrict__ kws,
    const u16* __restrict__ vws, u16* __restrict__ o_t)
{
    const int bh   = blockIdx.x;                 // x fastest -> XCD = bh%8
    const int tile = blockIdx.y;
    const int t    = threadIdx.x;
    const int wave = t >> 6, lane = t & 63;
    const int l15  = lane & 15, quad = lane >> 4;
    const int nb   = tile * 64 + wave * 16;      // this wave's query base

    // double buffer; per buffer: K[2][1024] | V[2][4096] u16 (interleaved)
    __shared__ __align__(16) u16 stg[2][10240];

    const u16* kb = &kws[bh * 3136 * 16];
    const u16* vb = &vws[bh * 64 * 3136];

    // K staging (r10 proven): 1 x 16B DMA per wave per 64-key chunk
    const int weff  = wave & 1;
    const int kkey  = lane >> 1;
    const int khalf = (lane & 1) ^ ((lane >> 3) & 1);
    const int kdst  = weff * 512;
    const int ksrc_row = weff * 32 + kkey;

    // V staging (r10 proven): 8 x 4B DMA per wave, relabel+row-xor placement
    const int vrow_off = lane >> 5;
    const int dwpos = lane & 31;
    const int p_oct = dwpos >> 2, w_i = dwpos & 3;

    // Q fragment (B-op): B[k=d=quad*8+j][n=query=l15]; zero for d>=16
    s16x8 aq = {0, 0, 0, 0, 0, 0, 0, 0};
    if (quad < 2)
        aq = *(const s16x8*)&qws[(bh * 3136 + nb + l15) * 16 + quad * 8];
    s16x8 ones;
    #pragma unroll
    for (int i = 0; i < 8; i++) ones[i] = (short)0x3F80;   // bf16 1.0

    f32x4 acc[4], acc5;                          // O^T tiles + rowsum tile
    #pragma unroll
    for (int dt = 0; dt < 4; dt++) acc[dt] = (f32x4){0.f, 0.f, 0.f, 0.f};
    acc5 = (f32x4){0.f, 0.f, 0.f, 0.f};

    auto stage64 = [&](int kbase, u16* sbk, u16* sbv) {
        #pragma unroll
        for (int s = 0; s < 2; s++) {
            #pragma unroll
            for (int h = 0; h < 4; h++) {
                const int m = (wave + s * 4) * 4 + h;        // pair idx 0..31
                const int d = 2 * m + vrow_off;
                const int gg = p_oct ^ (d & 7);
                const int src_dw = (gg >> 2) * 16 + ((w_i >> 1) & 1) * 8 +
                                   (gg & 3) * 2 + (w_i & 1);
                stage4(vb + d * 3136 + kbase + src_dw * 2, &sbv[m * 128]);
            }
        }
        stage16(kb + (kbase + ksrc_row) * 16 + khalf * 8, &sbk[kdst]);
    };
    auto stage_pair = [&](int p, int bsel) {     // chunks 2p, 2p+1 (clamped)
        u16* base = &stg[bsel][0];
        const int c0 = 2 * p;
        const int c1 = (2 * p + 1 < 49) ? (2 * p + 1) : 48;
        stage64(c0 * 64, base, base + 2048);
        stage64(c1 * 64, base + 1024, base + 2048 + 4096);
    };

    stage_pair(0, 0);
    __builtin_amdgcn_s_waitcnt(0x0F70);          // vmcnt(0): pair 0 landed

    for (int i = 0; i < 25; i++) {
        __builtin_amdgcn_s_barrier();            // pair i certified block-wide;
                                                 // prev readers of buf[(i+1)&1] done
        const int pn = (i + 1 < 25) ? (i + 1) : 24;
        stage_pair(pn, (i + 1) & 1);

        const u16* base = &stg[i & 1][0];
        const f32x4 z = {0.f, 0.f, 0.f, 0.f};
        #pragma unroll
        for (int sub = 0; sub < 2; sub++) {
            const u16* kc_ = base + sub * 1024;
            const u16* vc_ = base + 2048 + sub * 4096;

            // ---- S^T = K·Q^T : 4 key tiles of 16 (swapped operands)
            f32x4 s[4];
            #pragma unroll
            for (int ii = 0; ii < 4; ii++) {
                s16x8 kf = *(const s16x8*)&kc_[(ii * 16 + l15) * 16 +
                                               (((quad & 1) ^ ((l15 >> 2) & 1)) * 8)];
                s[ii] = mfma32(kf, aq, z);
            }

            // ---- P pack: pf[c32] = {exp2 s[2c32], exp2 s[2c32+1]}
            s16x8 pf[2];
            #pragma unroll
            for (int c32 = 0; c32 < 2; c32++) {
                #pragma unroll
                for (int r = 0; r < 4; r++) {
                    pf[c32][r]     = (short)f2bf_h(__builtin_amdgcn_exp2f(s[2 * c32][r]));
                    pf[c32][4 + r] = (short)f2bf_h(__builtin_amdgcn_exp2f(s[2 * c32 + 1][r]));
                }
            }
            if (i == 24 && sub == 1) {           // pad chunk 49: contribute 0
                pf[0] = (s16x8){0, 0, 0, 0, 0, 0, 0, 0};
                pf[1] = (s16x8){0, 0, 0, 0, 0, 0, 0, 0};
            }

            // ---- O^T += V^T·P ; rowsum via ones-MFMA
            #pragma unroll
            for (int c32 = 0; c32 < 2; c32++) {
                #pragma unroll
                for (int dt = 0; dt < 4; dt++) {
                    const int d = dt * 16 + l15;
                    const int pos = ((c32 * 4 + quad) ^ (d & 7)) * 8;
                    s16x8 vf = *(const s16x8*)&vc_[d * 64 + pos];
                    acc[dt] = mfma32(vf, pf[c32], acc[dt]);
                }
                acc5 = mfma32(ones, pf[c32], acc5);
            }
        }
        __builtin_amdgcn_s_waitcnt(0x0F70);      // vmcnt(0): own pair-(i+1) DMAs
    }                                            // (issued ~full iter ago: free)

    const float inv = 1.0f / acc5[0];            // rowsum for query l15

    // ---- epilogue (r9/r10 proven): O^T rows d=dt*16+quad*4+r, col l15
    u16* dst = &o_t[(((bh >> 3) * 3136) + nb + l15) * 512 + (bh & 7) * 64];
    #pragma unroll
    for (int dt = 0; dt < 4; dt++) {
        u16x4 o4;
        #pragma unroll
        for (int r = 0; r < 4; r++) o4[r] = f2bf(acc[dt][r] * inv);
        *(u16x4*)&dst[dt * 16 + quad * 4] = o4;
    }
}

// ---------------------------------------------------------------------------
// Output projection MFMA GEMM, no LDS, A hoisted. grid (98, 4, 2).
// A = wp' [256][512], B = o_t [n][512]; C[och][token] -> fp32 out.
// ---------------------------------------------------------------------------
__global__ __launch_bounds__(256, 4) void proj_kernel(
    const u16* __restrict__ o_t, const u16* __restrict__ wpb,
    const float* __restrict__ bp, float* __restrict__ out)
{
    const int b = blockIdx.z, n0 = blockIdx.x * 32;
    const int och0 = blockIdx.y * 64 + (threadIdx.x >> 6) * 16;
    const int lane = threadIdx.x & 63;
    const int l15 = lane & 15, quad = lane >> 4;
    const f32x4 z = {0.f, 0.f, 0.f, 0.f};

    const u16* arow = &wpb[(och0 + l15) * 512 + quad * 8];
    s16x8 a8[16];
    #pragma unroll
    for (int kc = 0; kc < 16; kc++) a8[kc] = *(const s16x8*)&arow[kc * 32];
    f32x4 acc[2] = {z, z};
    #pragma unroll
    for (int kc = 0; kc < 16; kc++) {
        #pragma unroll
        for (int f = 0; f < 2; f++) {
            s16x8 bf = *(const s16x8*)&o_t[(b * 3136 + n0 + f * 16 + l15) * 512 + kc * 32 + quad * 8];
            acc[f] = mfma32(a8[kc], bf, acc[f]);
        }
    }
    #pragma unroll
    for (int r = 0; r < 4; r++) {
        const int och = och0 + quad * 4 + r;
        const float bi = bp[och];
        #pragma unroll
        for (int f = 0; f < 2; f++)
            out[(b * 256 + och) * 3136 + n0 + f * 16 + l15] = acc[f][r] + bi;
    }
}

// ---------------------------------------------------------------------------
extern "C" void kernel_launch(void* const* d_in, const int* in_sizes, int n_in,
                              void* d_out, int out_size, void* d_ws, size_t ws_size,
                              hipStream_t stream) {
    const float* x  = (const float*)d_in[0];
    const float* wq = (const float*)d_in[1];
    const float* sq = (const float*)d_in[2];
    const float* bq = (const float*)d_in[3];
    const float* wk = (const float*)d_in[4];
    const float* sk = (const float*)d_in[5];
    const float* bk = (const float*)d_in[6];
    const float* wv = (const float*)d_in[7];
    const float* sv = (const float*)d_in[8];
    const float* bv = (const float*)d_in[9];
    const float* wp = (const float*)d_in[10];
    const float* sp = (const float*)d_in[11];
    const float* bp = (const float*)d_in[12];
    float* out = (float*)d_out;

    u16* qws = (u16*)d_ws;                 // 802816
    u16* kws = qws + 802816;               // 802816
    u16* vws = kws + 802816;               // 3211264
    u16* R   = vws + 3211264;              // 3211264 (x_t then o_t, overlaid)
    u16* xt  = R;
    u16* ot  = R;
    u16* wqb = R + 3211264;                // 32768
    u16* wkb = wqb + 32768;                // 32768
    u16* wvb = wkb + 32768;                // 131072
    u16* wpb = wvb + 131072;               // 131072  (total 16,711,680 B)

    xtw_kernel<<<dim3(49, 4, 3), 256, 0, stream>>>(x, xt, wq, sq, wk, sk,
                                                   wv, sv, wp, sp,
                                                   wqb, wkb, wvb, wpb);
    qkv_kernel<<<dim3(49, 12, 2), 256, 0, stream>>>(xt, wqb, wkb, wvb,
                                                    bq, bk, bv, qws, kws, vws);
    attn_kernel<<<dim3(16, 49), 256, 0, stream>>>(qws, kws, vws, ot);
    proj_kernel<<<dim3(98, 4, 2), 256, 0, stream>>>(ot, wpb, bp, out);
}